// Round 1
// baseline (3682.101 us; speedup 1.0000x reference)
//
#include <hip/hip_runtime.h>

#define NPT 4096
#define B_ 16
#define S_ 1024
#define K_ 32
#define ROWS (B_*S_*K_)   // 524288

// float readlane broadcast (SALU v_readlane -> scalar operand in FMA)
__device__ __forceinline__ float rlf(float v, int l) {
#if __has_builtin(__builtin_amdgcn_readlane)
  return __uint_as_float(__builtin_amdgcn_readlane(__float_as_uint(v), l));
#else
  return __shfl(v, l, 64);
#endif
}

// ---------------- FPS: one block per batch, 512 threads, 8 pts/thread ----------------
__global__ __launch_bounds__(512) void fps_kernel(const float* __restrict__ xyz,
    float* __restrict__ out0, float* __restrict__ new_xyz) {
  const int b = blockIdx.x, t = threadIdx.x;
  const int lane = t & 63, wv = t >> 6;
  const float* xb = xyz + (size_t)b * 3 * NPT;
  __shared__ float sx[NPT], sy[NPT], sz[NPT];
  __shared__ float s_val[2][8];
  __shared__ int   s_idx[2][8];
  float px[8], py[8], pz[8], dist[8];
#pragma unroll
  for (int i = 0; i < 8; i++) {
    int n = t + i * 512;
    px[i] = xb[n]; py[i] = xb[NPT + n]; pz[i] = xb[2 * NPT + n];
    sx[n] = px[i]; sy[n] = py[i]; sz[n] = pz[i];
    dist[i] = 1e10f;
  }
  __syncthreads();
  int far = 0;
  for (int it = 0; it < S_; ++it) {
    float cx = sx[far], cy = sy[far], cz = sz[far];
    if (t == 0) {
      out0[(b * 3 + 0) * S_ + it] = cx;
      out0[(b * 3 + 1) * S_ + it] = cy;
      out0[(b * 3 + 2) * S_ + it] = cz;
      float* nz = new_xyz + ((size_t)b * S_ + it) * 3;
      nz[0] = cx; nz[1] = cy; nz[2] = cz;
    }
    float bv = -1.f; int bi = 0;
#pragma unroll
    for (int i = 0; i < 8; i++) {
      // match ref op order: (dx*dx + dy*dy) + dz*dz, no FMA contraction
      float dx = __fadd_rn(px[i], -cx), dy = __fadd_rn(py[i], -cy), dz = __fadd_rn(pz[i], -cz);
      float d = __fadd_rn(__fadd_rn(__fmul_rn(dx, dx), __fmul_rn(dy, dy)), __fmul_rn(dz, dz));
      float nd = fminf(dist[i], d); dist[i] = nd;
      int n = t + i * 512;
      if (nd > bv || (nd == bv && n < bi)) { bv = nd; bi = n; }
    }
#pragma unroll
    for (int off = 32; off; off >>= 1) {   // wave butterfly argmax, min-index tiebreak
      float ov = __shfl_xor(bv, off); int oi = __shfl_xor(bi, off);
      if (ov > bv || (ov == bv && oi < bi)) { bv = ov; bi = oi; }
    }
    int p = it & 1;
    if (lane == 0) { s_val[p][wv] = bv; s_idx[p][wv] = bi; }
    __syncthreads();
    float v2 = (lane < 8) ? s_val[p][lane] : -2.f;
    int   i2 = (lane < 8) ? s_idx[p][lane] : 0;
#pragma unroll
    for (int off = 4; off; off >>= 1) {
      float ov = __shfl_xor(v2, off); int oi = __shfl_xor(i2, off);
      if (ov > v2 || (ov == v2 && oi < i2)) { v2 = ov; i2 = oi; }
    }
    far = __shfl(i2, 0);
  }
}

// ---------------- Ball query: one wave per query ----------------
__global__ __launch_bounds__(256) void ballq_kernel(const float* __restrict__ xyz,
    const float* __restrict__ new_xyz, int* __restrict__ gidx) {
  const int wid = (blockIdx.x * 256 + threadIdx.x) >> 6;   // 16384 queries
  const int lane = threadIdx.x & 63;
  const int b = wid >> 10;
  const float* xb = xyz + (size_t)b * 3 * NPT;
  const float qx = new_xyz[(size_t)wid * 3 + 0];
  const float qy = new_xyz[(size_t)wid * 3 + 1];
  const float qz = new_xyz[(size_t)wid * 3 + 2];
  const float R2 = (float)(0.4 * 0.4);
  int* g = gidx + (size_t)wid * K_;
  int cnt = 0, firstIdx = 0x7fffffff;
  for (int c0 = 0; c0 < NPT && cnt < K_; c0 += 64) {
    int n = c0 + lane;
    float dx = __fadd_rn(qx, -xb[n]);
    float dy = __fadd_rn(qy, -xb[NPT + n]);
    float dz = __fadd_rn(qz, -xb[2 * NPT + n]);
    float sq = __fadd_rn(__fadd_rn(__fmul_rn(dx, dx), __fmul_rn(dy, dy)), __fmul_rn(dz, dz));
    bool inr = !(sq > R2);
    unsigned long long m = __ballot(inr);
    if (inr) {
      int pos = cnt + (int)__popcll(m & ((1ull << lane) - 1ull));
      if (pos < K_) g[pos] = n;
    }
    if (firstIdx == 0x7fffffff && m) firstIdx = c0 + (int)__builtin_ctzll(m);
    cnt += (int)__popcll(m);
  }
  if (lane >= cnt && lane < K_) g[lane] = firstIdx;  // pad with first (always exists: self)
}

// ---------------- Layer 1: gather+concat fused, 6->64, emits partial stats ----------------
__global__ __launch_bounds__(256) void layer1_kernel(
    const float* __restrict__ xyz, const float* __restrict__ pts,
    const float* __restrict__ new_xyz, const int* __restrict__ gidx,
    const float* __restrict__ W1, const float* __restrict__ b1,
    float* __restrict__ y, float* __restrict__ partials) {
  __shared__ float sp[4 * 2 * 64];
  const int lane = threadIdx.x & 63, wv = threadIdx.x >> 6;
  const int nw = gridDim.x * 4;
  float w[6];
#pragma unroll
  for (int c = 0; c < 6; c++) w[c] = W1[lane * 6 + c];
  const float bias = b1[lane];
  float s0 = 0.f, s1 = 0.f;
  for (int r = blockIdx.x * 4 + wv; r < ROWS; r += nw) {
    int gi = gidx[r];
    int bs = r >> 5, b = bs >> 10;
    float v = 0.f;
    if (lane < 3)      v = xyz[((size_t)b * 3 + lane) * NPT + gi] - new_xyz[(size_t)bs * 3 + lane];
    else if (lane < 6) v = pts[((size_t)b * 3 + (lane - 3)) * NPT + gi];
    float acc = bias;
#pragma unroll
    for (int c = 0; c < 6; c++) acc = fmaf(rlf(v, c), w[c], acc);
    y[(size_t)r * 64 + lane] = acc;
    s0 += acc; s1 = fmaf(acc, acc, s1);
  }
  sp[(wv * 2 + 0) * 64 + lane] = s0;
  sp[(wv * 2 + 1) * 64 + lane] = s1;
  __syncthreads();
  if (threadIdx.x < 128) {
    float p = sp[threadIdx.x] + sp[threadIdx.x + 128] + sp[threadIdx.x + 256] + sp[threadIdx.x + 384];
    partials[(size_t)blockIdx.x * 128 + threadIdx.x] = p;
  }
}

// ---------------- Generic 64->COUT layer: bn+relu on input, W in registers ----------------
template <int NO, bool WRITE_OUT>
__global__ __launch_bounds__(256) void layer64_kernel(
    const float* in, const float* __restrict__ W,
    const float* __restrict__ bias, const float* __restrict__ bnin,
    float* out, float* __restrict__ partials, int nrows) {
  constexpr int COUT = NO * 64;
  __shared__ float sp[4 * 2 * COUT];
  const int lane = threadIdx.x & 63, wv = threadIdx.x >> 6;
  const int nw = gridDim.x * 4;
  float w[NO][64];
#pragma unroll
  for (int j = 0; j < NO; j++)
#pragma unroll
    for (int c = 0; c < 64; c++) w[j][c] = W[(size_t)(lane + j * 64) * 64 + c];
  const float isc = bnin[lane], ish = bnin[64 + lane];
  float br[NO], s0[NO], s1[NO];
#pragma unroll
  for (int j = 0; j < NO; j++) { br[j] = bias[lane + j * 64]; s0[j] = 0.f; s1[j] = 0.f; }
  for (int r = blockIdx.x * 4 + wv; r < nrows; r += nw) {
    float v = in[(size_t)r * 64 + lane];
    float z = fmaxf(fmaf(v, isc, ish), 0.f);
    float accA[NO], accB[NO];
#pragma unroll
    for (int j = 0; j < NO; j++) { accA[j] = br[j]; accB[j] = 0.f; }
#pragma unroll
    for (int c = 0; c < 64; c += 2) {
      float z0 = rlf(z, c), z1 = rlf(z, c + 1);
#pragma unroll
      for (int j = 0; j < NO; j++) {
        accA[j] = fmaf(z0, w[j][c], accA[j]);
        accB[j] = fmaf(z1, w[j][c + 1], accB[j]);
      }
    }
#pragma unroll
    for (int j = 0; j < NO; j++) {
      float a = accA[j] + accB[j];
      if (WRITE_OUT) out[(size_t)r * COUT + lane + j * 64] = a;
      s0[j] += a; s1[j] = fmaf(a, a, s1[j]);
    }
  }
#pragma unroll
  for (int j = 0; j < NO; j++) {
    sp[(wv * 2 + 0) * COUT + lane + j * 64] = s0[j];
    sp[(wv * 2 + 1) * COUT + lane + j * 64] = s1[j];
  }
  __syncthreads();
  for (int tt = threadIdx.x; tt < 2 * COUT; tt += 256) {
    float p = sp[tt] + sp[2 * COUT + tt] + sp[4 * COUT + tt] + sp[6 * COUT + tt];
    partials[(size_t)blockIdx.x * 2 * COUT + tt] = p;
  }
}

// ---------------- fold partials -> bn scale/shift ----------------
__global__ void finalize_kernel(const float* __restrict__ partials, int nblocks, int cout,
    const float* __restrict__ g, const float* __restrict__ be, float* __restrict__ bn) {
  int c = threadIdx.x;
  if (c >= cout) return;
  double s0 = 0.0, s1 = 0.0;
  for (int bb = 0; bb < nblocks; ++bb) {
    s0 += (double)partials[(size_t)bb * 2 * cout + c];
    s1 += (double)partials[(size_t)bb * 2 * cout + cout + c];
  }
  double N = (double)ROWS;
  double mean = s0 / N;
  double var = s1 / N - mean * mean;
  double scale = (double)g[c] / sqrt(var + 1e-5);
  bn[c] = (float)scale;
  bn[cout + c] = (float)((double)be[c] - mean * scale);
}

// ---------------- Layer 3 recompute + bn3 + relu + max over K + transposed store ----------------
__global__ __launch_bounds__(256) void l3max_kernel(const float* __restrict__ y2,
    const float* __restrict__ W3, const float* __restrict__ b3,
    const float* __restrict__ bn2, const float* __restrict__ bn3,
    float* __restrict__ out1) {
  const int lane = threadIdx.x & 63, wv = threadIdx.x >> 6;
  const int gq = blockIdx.x * 4 + wv;            // 16384 (b,s) groups; grid=4096
  float w0[64], w1[64];
#pragma unroll
  for (int c = 0; c < 64; c++) {
    w0[c] = W3[(size_t)lane * 64 + c];
    w1[c] = W3[(size_t)(lane + 64) * 64 + c];
  }
  const float isc = bn2[lane], ish = bn2[64 + lane];
  const float s3a = bn3[lane],      h3a = bn3[128 + lane];
  const float s3b = bn3[lane + 64], h3b = bn3[192 + lane];
  const float ba = b3[lane], bb = b3[lane + 64];
  float m0 = -1e30f, m1 = -1e30f;
  for (int k = 0; k < K_; k++) {
    size_t r = (size_t)gq * K_ + k;
    float v = y2[r * 64 + lane];
    float z = fmaxf(fmaf(v, isc, ish), 0.f);
    float a0 = ba, a1 = bb, c0 = 0.f, c1 = 0.f;
#pragma unroll
    for (int c = 0; c < 64; c += 2) {
      float z0 = rlf(z, c), z1 = rlf(z, c + 1);
      a0 = fmaf(z0, w0[c], a0);     a1 = fmaf(z0, w1[c], a1);
      c0 = fmaf(z1, w0[c + 1], c0); c1 = fmaf(z1, w1[c + 1], c1);
    }
    a0 += c0; a1 += c1;
    m0 = fmaxf(m0, fmaxf(fmaf(a0, s3a, h3a), 0.f));
    m1 = fmaxf(m1, fmaxf(fmaf(a1, s3b, h3b), 0.f));
  }
  __shared__ float tile[128 * 4];   // [ch][s_local]
  tile[lane * 4 + wv] = m0;
  tile[(lane + 64) * 4 + wv] = m1;
  __syncthreads();
  if (threadIdx.x < 128) {
    int b = blockIdx.x >> 8;            // 256 blocks per batch
    int s0i = (blockIdx.x & 255) * 4;
    float4 vv = *(float4*)&tile[threadIdx.x * 4];
    *(float4*)&out1[((size_t)b * 128 + threadIdx.x) * 1024 + s0i] = vv;
  }
}

extern "C" void kernel_launch(void* const* d_in, const int* in_sizes, int n_in,
                              void* d_out, int out_size, void* d_ws, size_t ws_size,
                              hipStream_t stream) {
  const float* xyz = (const float*)d_in[0];
  const float* pts = (const float*)d_in[1];
  const float* W1 = (const float*)d_in[2],  *b1 = (const float*)d_in[3];
  const float* g1 = (const float*)d_in[4],  *be1 = (const float*)d_in[5];
  const float* W2 = (const float*)d_in[6],  *b2 = (const float*)d_in[7];
  const float* g2 = (const float*)d_in[8],  *be2 = (const float*)d_in[9];
  const float* W3 = (const float*)d_in[10], *b3 = (const float*)d_in[11];
  const float* g3 = (const float*)d_in[12], *be3 = (const float*)d_in[13];
  float* out0 = (float*)d_out;                 // xyz_query_pc [16,3,1024]
  float* out1 = out0 + B_ * 3 * S_;            // new_points   [16,128,1024]

  char* ws = (char*)d_ws;
  float* new_xyz  = (float*)(ws);              // 49152 floats
  float* bn1      = (float*)(ws + 196608);     // 128
  float* bn2      = bn1 + 128;                 // 128
  float* bn3      = bn2 + 128;                 // 256
  int*   gidx     = (int*)(ws + 198656);       // 524288 ints
  float* partials = (float*)(ws + 2295808);    // up to 2048*256 floats
  float* y        = (float*)(ws + 4392960);    // 524288*64 floats (y1, then y2 in-place)

  fps_kernel<<<B_, 512, 0, stream>>>(xyz, out0, new_xyz);
  ballq_kernel<<<4096, 256, 0, stream>>>(xyz, new_xyz, gidx);
  layer1_kernel<<<2048, 256, 0, stream>>>(xyz, pts, new_xyz, gidx, W1, b1, y, partials);
  finalize_kernel<<<1, 128, 0, stream>>>(partials, 2048, 64, g1, be1, bn1);
  layer64_kernel<1, true><<<2048, 256, 0, stream>>>(y, W2, b2, bn1, y, partials, ROWS);
  finalize_kernel<<<1, 128, 0, stream>>>(partials, 2048, 64, g2, be2, bn2);
  layer64_kernel<2, false><<<2048, 256, 0, stream>>>(y, W3, b3, bn2, nullptr, partials, ROWS);
  finalize_kernel<<<1, 128, 0, stream>>>(partials, 2048, 128, g3, be3, bn3);
  l3max_kernel<<<4096, 256, 0, stream>>>(y, W3, b3, bn2, bn3, out1);
}

// Round 2
// 1710.660 us; speedup vs baseline: 2.1524x; 2.1524x over previous
//
#include <hip/hip_runtime.h>

#define NPT 4096
#define B_ 16
#define S_ 1024
#define K_ 32
#define ROWS (B_*S_*K_)   // 524288
#define PN 2048           // partial-stats blocks (layer kernels' grid)

// float readlane broadcast (SALU v_readlane -> scalar operand in FMA)
__device__ __forceinline__ float rlf(float v, int l) {
#if __has_builtin(__builtin_amdgcn_readlane)
  return __uint_as_float(__builtin_amdgcn_readlane(__float_as_uint(v), l));
#else
  return __shfl(v, l, 64);
#endif
}

#if defined(__has_builtin)
#if __has_builtin(__builtin_amdgcn_update_dpp)
#define HAS_DPP 1
#endif
#endif

__device__ __forceinline__ void cmpsel(float ov, int oi, float& bv, int& bi) {
  if (ov > bv || (ov == bv && oi < bi)) { bv = ov; bi = oi; }
}

#ifdef HAS_DPP
#define DPPSTEP(CTRL) { \
  float ov = __int_as_float(__builtin_amdgcn_update_dpp(__float_as_int(bv), __float_as_int(bv), (CTRL), 0xF, 0xF, false)); \
  int   oi = __builtin_amdgcn_update_dpp(bi, bi, (CTRL), 0xF, 0xF, false); \
  cmpsel(ov, oi, bv, bi); }
// full-wave argmax -> result in lane 63
__device__ __forceinline__ void wave_argmax(float& bv, int& bi) {
  DPPSTEP(0x111); DPPSTEP(0x112); DPPSTEP(0x114); DPPSTEP(0x118); // row_shr 1,2,4,8
  DPPSTEP(0x142); DPPSTEP(0x143);                                  // row_bcast15, row_bcast31
}
// 8-entry argmax (entries replicated at lane&7) -> result in lane 7 (uniform-ish)
__device__ __forceinline__ void argmax8(float& bv, int& bi) {
  DPPSTEP(0x111); DPPSTEP(0x112); DPPSTEP(0x114);                  // row_shr 1,2,4
}
#define WAVE_WINNER_LANE 63
#else
__device__ __forceinline__ void wave_argmax(float& bv, int& bi) {
#pragma unroll
  for (int off = 32; off; off >>= 1) {
    float ov = __shfl_xor(bv, off); int oi = __shfl_xor(bi, off);
    cmpsel(ov, oi, bv, bi);
  }
}
__device__ __forceinline__ void argmax8(float& bv, int& bi) {
#pragma unroll
  for (int off = 4; off; off >>= 1) {
    float ov = __shfl_xor(bv, off); int oi = __shfl_xor(bi, off);
    cmpsel(ov, oi, bv, bi);
  }
}
#define WAVE_WINNER_LANE 63
#endif

__device__ __forceinline__ int bcast_lane_i(int v, int l) {
#if __has_builtin(__builtin_amdgcn_readlane)
  return __builtin_amdgcn_readlane(v, l);
#else
  return __shfl(v, l, 64);
#endif
}

// ---------------- FPS: one block per batch, 512 threads, 8 pts/thread ----------------
__global__ __launch_bounds__(512) void fps_kernel(const float* __restrict__ xyz,
    float* __restrict__ out0, float* __restrict__ new_xyz) {
  const int b = blockIdx.x, t = threadIdx.x;
  const int lane = t & 63, wv = t >> 6;
  const float* xb = xyz + (size_t)b * 3 * NPT;
  __shared__ float sx[NPT], sy[NPT], sz[NPT];
  __shared__ float s_val[2][8];
  __shared__ int   s_idx[2][8];
  // coalesced stage into LDS
#pragma unroll
  for (int j = 0; j < 8; j++) {
    int m = t + j * 512;
    sx[m] = xb[m]; sy[m] = xb[NPT + m]; sz[m] = xb[2 * NPT + m];
  }
  __syncthreads();
  // lane-local consecutive points: n = t*8 + i
  float px[8], py[8], pz[8], dist[8];
  const int base = t * 8;
#pragma unroll
  for (int i = 0; i < 8; i++) {
    px[i] = sx[base + i]; py[i] = sy[base + i]; pz[i] = sz[base + i];
    dist[i] = 1e10f;
  }
  int far = 0;
  for (int it = 0; it < S_; ++it) {
    float cx = sx[far], cy = sy[far], cz = sz[far];
    if (t == 0) {
      out0[(b * 3 + 0) * S_ + it] = cx;
      out0[(b * 3 + 1) * S_ + it] = cy;
      out0[(b * 3 + 2) * S_ + it] = cz;
      float* nz = new_xyz + ((size_t)b * S_ + it) * 3;
      nz[0] = cx; nz[1] = cy; nz[2] = cz;
    }
    float bv = -1.f; int bi = base;
#pragma unroll
    for (int i = 0; i < 8; i++) {
      // match ref op order: (dx*dx + dy*dy) + dz*dz, no FMA contraction
      float dx = __fadd_rn(px[i], -cx), dy = __fadd_rn(py[i], -cy), dz = __fadd_rn(pz[i], -cz);
      float d = __fadd_rn(__fadd_rn(__fmul_rn(dx, dx), __fmul_rn(dy, dy)), __fmul_rn(dz, dz));
      float nd = fminf(dist[i], d); dist[i] = nd;
      if (nd > bv) { bv = nd; bi = base + i; }   // strictly greater => first max => min local idx
    }
    wave_argmax(bv, bi);                          // winner in lane 63 (DPP) / all lanes (fallback)
    int p = it & 1;
    if (lane == WAVE_WINNER_LANE) { s_val[p][wv] = bv; s_idx[p][wv] = bi; }
    __syncthreads();
    // every wave reduces the 8 wave-winners itself (no second barrier)
    float v2 = s_val[p][lane & 7];
    int   i2 = s_idx[p][lane & 7];
    argmax8(v2, i2);
    far = bcast_lane_i(i2, 7);
  }
}

// ---------------- Ball query: one wave per query ----------------
__global__ __launch_bounds__(256) void ballq_kernel(const float* __restrict__ xyz,
    const float* __restrict__ new_xyz, int* __restrict__ gidx) {
  const int wid = (blockIdx.x * 256 + threadIdx.x) >> 6;   // 16384 queries
  const int lane = threadIdx.x & 63;
  const int b = wid >> 10;
  const float* xb = xyz + (size_t)b * 3 * NPT;
  const float qx = new_xyz[(size_t)wid * 3 + 0];
  const float qy = new_xyz[(size_t)wid * 3 + 1];
  const float qz = new_xyz[(size_t)wid * 3 + 2];
  const float R2 = (float)(0.4 * 0.4);
  int* g = gidx + (size_t)wid * K_;
  int cnt = 0, firstIdx = 0x7fffffff;
  for (int c0 = 0; c0 < NPT && cnt < K_; c0 += 64) {
    int n = c0 + lane;
    float dx = __fadd_rn(qx, -xb[n]);
    float dy = __fadd_rn(qy, -xb[NPT + n]);
    float dz = __fadd_rn(qz, -xb[2 * NPT + n]);
    float sq = __fadd_rn(__fadd_rn(__fmul_rn(dx, dx), __fmul_rn(dy, dy)), __fmul_rn(dz, dz));
    bool inr = !(sq > R2);
    unsigned long long m = __ballot(inr);
    if (inr) {
      int pos = cnt + (int)__popcll(m & ((1ull << lane) - 1ull));
      if (pos < K_) g[pos] = n;
    }
    if (firstIdx == 0x7fffffff && m) firstIdx = c0 + (int)__builtin_ctzll(m);
    cnt += (int)__popcll(m);
  }
  if (lane >= cnt && lane < K_) g[lane] = firstIdx;  // pad with first (always exists: self)
}

// ---------------- Layer 1: gather+concat fused, 6->64, emits partial stats ----------------
__global__ __launch_bounds__(256) void layer1_kernel(
    const float* __restrict__ xyz, const float* __restrict__ pts,
    const float* __restrict__ new_xyz, const int* __restrict__ gidx,
    const float* __restrict__ W1, const float* __restrict__ b1,
    float* __restrict__ y, float* __restrict__ partials) {
  __shared__ float sp[4 * 2 * 64];
  const int lane = threadIdx.x & 63, wv = threadIdx.x >> 6;
  const int nw = gridDim.x * 4;
  float w[6];
#pragma unroll
  for (int c = 0; c < 6; c++) w[c] = W1[lane * 6 + c];
  const float bias = b1[lane];
  float s0 = 0.f, s1 = 0.f;
  for (int r = blockIdx.x * 4 + wv; r < ROWS; r += nw) {
    int gi = gidx[r];
    int bs = r >> 5, b = bs >> 10;
    float v = 0.f;
    if (lane < 3)      v = xyz[((size_t)b * 3 + lane) * NPT + gi] - new_xyz[(size_t)bs * 3 + lane];
    else if (lane < 6) v = pts[((size_t)b * 3 + (lane - 3)) * NPT + gi];
    float acc = bias;
#pragma unroll
    for (int c = 0; c < 6; c++) acc = fmaf(rlf(v, c), w[c], acc);
    y[(size_t)r * 64 + lane] = acc;
    s0 += acc; s1 = fmaf(acc, acc, s1);
  }
  sp[(wv * 2 + 0) * 64 + lane] = s0;
  sp[(wv * 2 + 1) * 64 + lane] = s1;
  __syncthreads();
  if (threadIdx.x < 128) {
    float p = sp[threadIdx.x] + sp[threadIdx.x + 128] + sp[threadIdx.x + 256] + sp[threadIdx.x + 384];
    partials[(size_t)threadIdx.x * PN + blockIdx.x] = p;   // transposed: [stat_row][block]
  }
}

// ---------------- Generic 64->COUT layer: bn+relu on input, W in registers ----------------
template <int NO, bool WRITE_OUT>
__global__ __launch_bounds__(256) void layer64_kernel(
    const float* in, const float* __restrict__ W,
    const float* __restrict__ bias, const float* __restrict__ bnin,
    float* out, float* __restrict__ partials, int nrows) {
  constexpr int COUT = NO * 64;
  __shared__ float sp[4 * 2 * COUT];
  const int lane = threadIdx.x & 63, wv = threadIdx.x >> 6;
  const int nw = gridDim.x * 4;
  float w[NO][64];
#pragma unroll
  for (int j = 0; j < NO; j++)
#pragma unroll
    for (int c = 0; c < 64; c++) w[j][c] = W[(size_t)(lane + j * 64) * 64 + c];
  const float isc = bnin[lane], ish = bnin[64 + lane];
  float br[NO], s0[NO], s1[NO];
#pragma unroll
  for (int j = 0; j < NO; j++) { br[j] = bias[lane + j * 64]; s0[j] = 0.f; s1[j] = 0.f; }
  for (int r = blockIdx.x * 4 + wv; r < nrows; r += nw) {
    float v = in[(size_t)r * 64 + lane];
    float z = fmaxf(fmaf(v, isc, ish), 0.f);
    float accA[NO], accB[NO];
#pragma unroll
    for (int j = 0; j < NO; j++) { accA[j] = br[j]; accB[j] = 0.f; }
#pragma unroll
    for (int c = 0; c < 64; c += 2) {
      float z0 = rlf(z, c), z1 = rlf(z, c + 1);
#pragma unroll
      for (int j = 0; j < NO; j++) {
        accA[j] = fmaf(z0, w[j][c], accA[j]);
        accB[j] = fmaf(z1, w[j][c + 1], accB[j]);
      }
    }
#pragma unroll
    for (int j = 0; j < NO; j++) {
      float a = accA[j] + accB[j];
      if (WRITE_OUT) out[(size_t)r * COUT + lane + j * 64] = a;
      s0[j] += a; s1[j] = fmaf(a, a, s1[j]);
    }
  }
#pragma unroll
  for (int j = 0; j < NO; j++) {
    sp[(wv * 2 + 0) * COUT + lane + j * 64] = s0[j];
    sp[(wv * 2 + 1) * COUT + lane + j * 64] = s1[j];
  }
  __syncthreads();
  for (int tt = threadIdx.x; tt < 2 * COUT; tt += 256) {
    float p = sp[tt] + sp[2 * COUT + tt] + sp[4 * COUT + tt] + sp[6 * COUT + tt];
    partials[(size_t)tt * PN + blockIdx.x] = p;            // transposed: [stat_row][block]
  }
}

// ---------------- fold partials -> bn scale/shift (one block per channel) ----------------
__global__ __launch_bounds__(256) void finalize_kernel(const float* __restrict__ partials,
    int cout, const float* __restrict__ g, const float* __restrict__ be,
    float* __restrict__ bn) {
  const int c = blockIdx.x;            // 0..cout-1
  const int t = threadIdx.x;
  const int lane = t & 63, wv = t >> 6;
  float s0 = 0.f, s1 = 0.f;
  for (int bb = t; bb < PN; bb += 256) {
    s0 += partials[(size_t)c * PN + bb];
    s1 += partials[(size_t)(cout + c) * PN + bb];
  }
#pragma unroll
  for (int off = 32; off; off >>= 1) {
    s0 += __shfl_xor(s0, off);
    s1 += __shfl_xor(s1, off);
  }
  __shared__ float r0[4], r1[4];
  if (lane == 0) { r0[wv] = s0; r1[wv] = s1; }
  __syncthreads();
  if (t == 0) {
    double d0 = (double)r0[0] + r0[1] + r0[2] + r0[3];
    double d1 = (double)r1[0] + r1[1] + r1[2] + r1[3];
    double N = (double)ROWS;
    double mean = d0 / N;
    double var = d1 / N - mean * mean;
    double scale = (double)g[c] / sqrt(var + 1e-5);
    bn[c] = (float)scale;
    bn[cout + c] = (float)((double)be[c] - mean * scale);
  }
}

// ---------------- Layer 3 recompute + bn3 + relu + max over K + transposed store ----------------
__global__ __launch_bounds__(256) void l3max_kernel(const float* __restrict__ y2,
    const float* __restrict__ W3, const float* __restrict__ b3,
    const float* __restrict__ bn2, const float* __restrict__ bn3,
    float* __restrict__ out1) {
  const int lane = threadIdx.x & 63, wv = threadIdx.x >> 6;
  const int gq = blockIdx.x * 4 + wv;            // 16384 (b,s) groups; grid=4096
  float w0[64], w1[64];
#pragma unroll
  for (int c = 0; c < 64; c++) {
    w0[c] = W3[(size_t)lane * 64 + c];
    w1[c] = W3[(size_t)(lane + 64) * 64 + c];
  }
  const float isc = bn2[lane], ish = bn2[64 + lane];
  const float s3a = bn3[lane],      h3a = bn3[128 + lane];
  const float s3b = bn3[lane + 64], h3b = bn3[192 + lane];
  const float ba = b3[lane], bb = b3[lane + 64];
  float m0 = -1e30f, m1 = -1e30f;
  for (int k = 0; k < K_; k++) {
    size_t r = (size_t)gq * K_ + k;
    float v = y2[r * 64 + lane];
    float z = fmaxf(fmaf(v, isc, ish), 0.f);
    float a0 = ba, a1 = bb, c0 = 0.f, c1 = 0.f;
#pragma unroll
    for (int c = 0; c < 64; c += 2) {
      float z0 = rlf(z, c), z1 = rlf(z, c + 1);
      a0 = fmaf(z0, w0[c], a0);     a1 = fmaf(z0, w1[c], a1);
      c0 = fmaf(z1, w0[c + 1], c0); c1 = fmaf(z1, w1[c + 1], c1);
    }
    a0 += c0; a1 += c1;
    m0 = fmaxf(m0, fmaxf(fmaf(a0, s3a, h3a), 0.f));
    m1 = fmaxf(m1, fmaxf(fmaf(a1, s3b, h3b), 0.f));
  }
  __shared__ float tile[128 * 4];   // [ch][s_local]
  tile[lane * 4 + wv] = m0;
  tile[(lane + 64) * 4 + wv] = m1;
  __syncthreads();
  if (threadIdx.x < 128) {
    int b = blockIdx.x >> 8;            // 256 blocks per batch
    int s0i = (blockIdx.x & 255) * 4;
    float4 vv = *(float4*)&tile[threadIdx.x * 4];
    *(float4*)&out1[((size_t)b * 128 + threadIdx.x) * 1024 + s0i] = vv;
  }
}

extern "C" void kernel_launch(void* const* d_in, const int* in_sizes, int n_in,
                              void* d_out, int out_size, void* d_ws, size_t ws_size,
                              hipStream_t stream) {
  const float* xyz = (const float*)d_in[0];
  const float* pts = (const float*)d_in[1];
  const float* W1 = (const float*)d_in[2],  *b1 = (const float*)d_in[3];
  const float* g1 = (const float*)d_in[4],  *be1 = (const float*)d_in[5];
  const float* W2 = (const float*)d_in[6],  *b2 = (const float*)d_in[7];
  const float* g2 = (const float*)d_in[8],  *be2 = (const float*)d_in[9];
  const float* W3 = (const float*)d_in[10], *b3 = (const float*)d_in[11];
  const float* g3 = (const float*)d_in[12], *be3 = (const float*)d_in[13];
  float* out0 = (float*)d_out;                 // xyz_query_pc [16,3,1024]
  float* out1 = out0 + B_ * 3 * S_;            // new_points   [16,128,1024]

  char* ws = (char*)d_ws;
  float* new_xyz  = (float*)(ws);              // 49152 floats
  float* bn1      = (float*)(ws + 196608);     // 128
  float* bn2      = bn1 + 128;                 // 128
  float* bn3      = bn2 + 128;                 // 256
  int*   gidx     = (int*)(ws + 198656);       // 524288 ints
  float* partials = (float*)(ws + 2295808);    // 256*PN floats max
  float* y        = (float*)(ws + 4392960);    // 524288*64 floats (y1, then y2 in-place)

  fps_kernel<<<B_, 512, 0, stream>>>(xyz, out0, new_xyz);
  ballq_kernel<<<4096, 256, 0, stream>>>(xyz, new_xyz, gidx);
  layer1_kernel<<<PN, 256, 0, stream>>>(xyz, pts, new_xyz, gidx, W1, b1, y, partials);
  finalize_kernel<<<64, 256, 0, stream>>>(partials, 64, g1, be1, bn1);
  layer64_kernel<1, true><<<PN, 256, 0, stream>>>(y, W2, b2, bn1, y, partials, ROWS);
  finalize_kernel<<<64, 256, 0, stream>>>(partials, 64, g2, be2, bn2);
  layer64_kernel<2, false><<<PN, 256, 0, stream>>>(y, W3, b3, bn2, nullptr, partials, ROWS);
  finalize_kernel<<<128, 256, 0, stream>>>(partials, 128, g3, be3, bn3);
  l3max_kernel<<<4096, 256, 0, stream>>>(y, W3, b3, bn2, bn3, out1);
}

// Round 4
// 1359.735 us; speedup vs baseline: 2.7080x; 1.2581x over previous
//
#include <hip/hip_runtime.h>

#pragma clang fp contract(off)

#define NPT 4096
#define B_ 16
#define S_ 1024
#define K_ 32
#define ROWS (B_*S_*K_)   // 524288
#define PN 2048           // partial-stats blocks (layer kernels' grid)

typedef float v2f __attribute__((ext_vector_type(2)));
typedef unsigned int u32;
typedef unsigned long long u64;

// float readlane broadcast (SALU v_readlane -> scalar operand in FMA)
__device__ __forceinline__ float rlf(float v, int l) {
#if __has_builtin(__builtin_amdgcn_readlane)
  return __uint_as_float(__builtin_amdgcn_readlane(__float_as_uint(v), l));
#else
  return __shfl(v, l, 64);
#endif
}

#if defined(__has_builtin)
#if __has_builtin(__builtin_amdgcn_update_dpp)
#define HAS_DPP 1
#endif
#endif

#ifdef HAS_DPP
template <int CTRL>
__device__ __forceinline__ u64 dpp_u64(u64 x) {
  int lo = (int)(u32)x, hi = (int)(u32)(x >> 32);
  lo = __builtin_amdgcn_update_dpp(lo, lo, CTRL, 0xF, 0xF, false);
  hi = __builtin_amdgcn_update_dpp(hi, hi, CTRL, 0xF, 0xF, false);
  return ((u64)(u32)hi << 32) | (u32)lo;
}
// full-wave max -> lane 63 (row_shr chain + row_bcast)
__device__ __forceinline__ u64 wave_max_u64(u64 k) {
  u64 o;
  o = dpp_u64<0x111>(k); if (o > k) k = o;  // row_shr:1
  o = dpp_u64<0x112>(k); if (o > k) k = o;  // row_shr:2
  o = dpp_u64<0x114>(k); if (o > k) k = o;  // row_shr:4
  o = dpp_u64<0x118>(k); if (o > k) k = o;  // row_shr:8
  o = dpp_u64<0x142>(k); if (o > k) k = o;  // row_bcast:15
  o = dpp_u64<0x143>(k); if (o > k) k = o;  // row_bcast:31
  return k;
}
#else
__device__ __forceinline__ u64 wave_max_u64(u64 k) {
#pragma unroll
  for (int off = 32; off; off >>= 1) {
    u64 o = (((u64)(u32)__shfl_xor((int)(k >> 32), off)) << 32) |
            (u32)__shfl_xor((int)(u32)k, off);
    if (o > k) k = o;
  }
  return k;
}
#endif

// ---------------- FPS: one block per batch, 512 threads, 8 pts/thread ----------------
__global__ __launch_bounds__(512) void fps_kernel(const float* __restrict__ xyz,
    float* __restrict__ out0, float* __restrict__ new_xyz) {
  const int b = blockIdx.x, t = threadIdx.x;
  const int lane = t & 63;
  const float* xb = xyz + (size_t)b * 3 * NPT;
  __shared__ float4 spt[NPT];       // 64 KB: (x,y,z,-)
  __shared__ u64 skey[3];           // 3-slot rotating argmax cell
  __shared__ int sfar[S_];          // selected index per iteration
  // coalesced stage into LDS
#pragma unroll
  for (int j = 0; j < 8; j++) {
    int m = t + j * 512;
    spt[m] = make_float4(xb[m], xb[NPT + m], xb[2 * NPT + m], 0.f);
  }
  if (t < 3) skey[t] = 0ull;
  __syncthreads();
  // lane-local consecutive points: n = t*8 + i, held as float2 pairs for v_pk ops
  v2f px[4], py[4], pz[4], ds[4];
  const int base = t * 8;
#pragma unroll
  for (int j = 0; j < 4; j++) {
    float4 p0 = spt[base + 2 * j], p1 = spt[base + 2 * j + 1];
    px[j] = (v2f){p0.x, p1.x}; py[j] = (v2f){p0.y, p1.y}; pz[j] = (v2f){p0.z, p1.z};
    ds[j] = (v2f){1e10f, 1e10f};
  }
  int far = 0;
  int slot = 0;
  for (int it = 0; it < S_; ++it) {
    if (t == 0) sfar[it] = far;
    float4 c = spt[far];
    v2f cx = (v2f){c.x, c.x}, cy = (v2f){c.y, c.y}, cz = (v2f){c.z, c.z};
    float bv = -1.f; int bi = 0;
#pragma unroll
    for (int j = 0; j < 4; j++) {
      // exact ref op order per element: ((dx*dx + dy*dy) + dz*dz), contraction OFF
      v2f dx = px[j] - cx, dy = py[j] - cy, dz = pz[j] - cz;
      v2f s = dx * dx + dy * dy;
      v2f d = s + dz * dz;
      v2f nd;
      nd.x = fminf(ds[j].x, d.x);
      nd.y = fminf(ds[j].y, d.y);
      ds[j] = nd;
      if (nd.x > bv) { bv = nd.x; bi = 2 * j; }       // strictly-greater => min local idx
      if (nd.y > bv) { bv = nd.y; bi = 2 * j + 1; }
    }
    // sortable key: max dist, tie -> min index
    u64 key = ((u64)__float_as_uint(bv) << 32) | (u32)(~(base + bi));
    key = wave_max_u64(key);
    if (lane == 63) atomicMax(&skey[slot], key);
    __syncthreads();
    u64 k = skey[slot];
    if (t == 0) skey[slot == 0 ? 2 : slot - 1] = 0ull;  // reset slot (it+2)%3: safe post-barrier
    far = (int)(~(u32)k);
    slot = (slot == 2) ? 0 : slot + 1;
  }
  __syncthreads();
  // coalesced writeback of centroids
#pragma unroll
  for (int j = 0; j < 2; j++) {
    int it = t + j * 512;
    float4 p = spt[sfar[it]];
    out0[(b * 3 + 0) * S_ + it] = p.x;
    out0[(b * 3 + 1) * S_ + it] = p.y;
    out0[(b * 3 + 2) * S_ + it] = p.z;
    float* nz = new_xyz + ((size_t)b * S_ + it) * 3;
    nz[0] = p.x; nz[1] = p.y; nz[2] = p.z;
  }
}

// ---------------- Ball query: one wave per query ----------------
__global__ __launch_bounds__(256) void ballq_kernel(const float* __restrict__ xyz,
    const float* __restrict__ new_xyz, int* __restrict__ gidx) {
  const int wid = (blockIdx.x * 256 + threadIdx.x) >> 6;   // 16384 queries
  const int lane = threadIdx.x & 63;
  const int b = wid >> 10;
  const float* xb = xyz + (size_t)b * 3 * NPT;
  const float qx = new_xyz[(size_t)wid * 3 + 0];
  const float qy = new_xyz[(size_t)wid * 3 + 1];
  const float qz = new_xyz[(size_t)wid * 3 + 2];
  const float R2 = (float)(0.4 * 0.4);
  int* g = gidx + (size_t)wid * K_;
  int cnt = 0, firstIdx = 0x7fffffff;
  for (int c0 = 0; c0 < NPT && cnt < K_; c0 += 64) {
    int n = c0 + lane;
    float dx = __fadd_rn(qx, -xb[n]);
    float dy = __fadd_rn(qy, -xb[NPT + n]);
    float dz = __fadd_rn(qz, -xb[2 * NPT + n]);
    float sq = __fadd_rn(__fadd_rn(__fmul_rn(dx, dx), __fmul_rn(dy, dy)), __fmul_rn(dz, dz));
    bool inr = !(sq > R2);
    unsigned long long m = __ballot(inr);
    if (inr) {
      int pos = cnt + (int)__popcll(m & ((1ull << lane) - 1ull));
      if (pos < K_) g[pos] = n;
    }
    if (firstIdx == 0x7fffffff && m) firstIdx = c0 + (int)__builtin_ctzll(m);
    cnt += (int)__popcll(m);
  }
  if (lane >= cnt && lane < K_) g[lane] = firstIdx;  // pad with first (always exists: self)
}

// ---------------- Layer 1: gather+concat fused, 6->64, emits partial stats ----------------
__global__ __launch_bounds__(256) void layer1_kernel(
    const float* __restrict__ xyz, const float* __restrict__ pts,
    const float* __restrict__ new_xyz, const int* __restrict__ gidx,
    const float* __restrict__ W1, const float* __restrict__ b1,
    float* __restrict__ y, float* __restrict__ partials) {
  __shared__ float sp[4 * 2 * 64];
  const int lane = threadIdx.x & 63, wv = threadIdx.x >> 6;
  const int nw = gridDim.x * 4;
  float w[6];
#pragma unroll
  for (int c = 0; c < 6; c++) w[c] = W1[lane * 6 + c];
  const float bias = b1[lane];
  float s0 = 0.f, s1 = 0.f;
  for (int r = blockIdx.x * 4 + wv; r < ROWS; r += nw) {
    int gi = gidx[r];
    int bs = r >> 5, b = bs >> 10;
    float v = 0.f;
    if (lane < 3)      v = xyz[((size_t)b * 3 + lane) * NPT + gi] - new_xyz[(size_t)bs * 3 + lane];
    else if (lane < 6) v = pts[((size_t)b * 3 + (lane - 3)) * NPT + gi];
    float acc = bias;
#pragma unroll
    for (int c = 0; c < 6; c++) acc = fmaf(rlf(v, c), w[c], acc);
    y[(size_t)r * 64 + lane] = acc;
    s0 += acc; s1 = fmaf(acc, acc, s1);
  }
  sp[(wv * 2 + 0) * 64 + lane] = s0;
  sp[(wv * 2 + 1) * 64 + lane] = s1;
  __syncthreads();
  if (threadIdx.x < 128) {
    float p = sp[threadIdx.x] + sp[threadIdx.x + 128] + sp[threadIdx.x + 256] + sp[threadIdx.x + 384];
    partials[(size_t)threadIdx.x * PN + blockIdx.x] = p;   // transposed: [stat_row][block]
  }
}

// ---------------- Generic 64->COUT layer: bn+relu on input, W in registers ----------------
template <int NO, bool WRITE_OUT>
__global__ __launch_bounds__(256) void layer64_kernel(
    const float* in, const float* __restrict__ W,
    const float* __restrict__ bias, const float* __restrict__ bnin,
    float* out, float* __restrict__ partials, int nrows) {
  constexpr int COUT = NO * 64;
  __shared__ float sp[4 * 2 * COUT];
  const int lane = threadIdx.x & 63, wv = threadIdx.x >> 6;
  const int nw = gridDim.x * 4;
  float w[NO][64];
#pragma unroll
  for (int j = 0; j < NO; j++)
#pragma unroll
    for (int c = 0; c < 64; c++) w[j][c] = W[(size_t)(lane + j * 64) * 64 + c];
  const float isc = bnin[lane], ish = bnin[64 + lane];
  float br[NO], s0[NO], s1[NO];
#pragma unroll
  for (int j = 0; j < NO; j++) { br[j] = bias[lane + j * 64]; s0[j] = 0.f; s1[j] = 0.f; }
  for (int r = blockIdx.x * 4 + wv; r < nrows; r += nw) {
    float v = in[(size_t)r * 64 + lane];
    float z = fmaxf(fmaf(v, isc, ish), 0.f);
    float accA[NO], accB[NO];
#pragma unroll
    for (int j = 0; j < NO; j++) { accA[j] = br[j]; accB[j] = 0.f; }
#pragma unroll
    for (int c = 0; c < 64; c += 2) {
      float z0 = rlf(z, c), z1 = rlf(z, c + 1);
#pragma unroll
      for (int j = 0; j < NO; j++) {
        accA[j] = fmaf(z0, w[j][c], accA[j]);
        accB[j] = fmaf(z1, w[j][c + 1], accB[j]);
      }
    }
#pragma unroll
    for (int j = 0; j < NO; j++) {
      float a = accA[j] + accB[j];
      if (WRITE_OUT) out[(size_t)r * COUT + lane + j * 64] = a;
      s0[j] += a; s1[j] = fmaf(a, a, s1[j]);
    }
  }
#pragma unroll
  for (int j = 0; j < NO; j++) {
    sp[(wv * 2 + 0) * COUT + lane + j * 64] = s0[j];
    sp[(wv * 2 + 1) * COUT + lane + j * 64] = s1[j];
  }
  __syncthreads();
  for (int tt = threadIdx.x; tt < 2 * COUT; tt += 256) {
    float p = sp[tt] + sp[2 * COUT + tt] + sp[4 * COUT + tt] + sp[6 * COUT + tt];
    partials[(size_t)tt * PN + blockIdx.x] = p;            // transposed: [stat_row][block]
  }
}

// ---------------- fold partials -> bn scale/shift (one block per channel) ----------------
__global__ __launch_bounds__(256) void finalize_kernel(const float* __restrict__ partials,
    int cout, const float* __restrict__ g, const float* __restrict__ be,
    float* __restrict__ bn) {
  const int c = blockIdx.x;            // 0..cout-1
  const int t = threadIdx.x;
  const int lane = t & 63, wv = t >> 6;
  float s0 = 0.f, s1 = 0.f;
  for (int bb = t; bb < PN; bb += 256) {
    s0 += partials[(size_t)c * PN + bb];
    s1 += partials[(size_t)(cout + c) * PN + bb];
  }
#pragma unroll
  for (int off = 32; off; off >>= 1) {
    s0 += __shfl_xor(s0, off);
    s1 += __shfl_xor(s1, off);
  }
  __shared__ float r0[4], r1[4];
  if (lane == 0) { r0[wv] = s0; r1[wv] = s1; }
  __syncthreads();
  if (t == 0) {
    double d0 = (double)r0[0] + r0[1] + r0[2] + r0[3];
    double d1 = (double)r1[0] + r1[1] + r1[2] + r1[3];
    double N = (double)ROWS;
    double mean = d0 / N;
    double var = d1 / N - mean * mean;
    double scale = (double)g[c] / sqrt(var + 1e-5);
    bn[c] = (float)scale;
    bn[cout + c] = (float)((double)be[c] - mean * scale);
  }
}

// ---------------- Layer 3 recompute + bn3 + relu + max over K + transposed store ----------------
__global__ __launch_bounds__(256) void l3max_kernel(const float* __restrict__ y2,
    const float* __restrict__ W3, const float* __restrict__ b3,
    const float* __restrict__ bn2, const float* __restrict__ bn3,
    float* __restrict__ out1) {
  const int lane = threadIdx.x & 63, wv = threadIdx.x >> 6;
  const int gq = blockIdx.x * 4 + wv;            // 16384 (b,s) groups; grid=4096
  float w0[64], w1[64];
#pragma unroll
  for (int c = 0; c < 64; c++) {
    w0[c] = W3[(size_t)lane * 64 + c];
    w1[c] = W3[(size_t)(lane + 64) * 64 + c];
  }
  const float isc = bn2[lane], ish = bn2[64 + lane];
  const float s3a = bn3[lane],      h3a = bn3[128 + lane];
  const float s3b = bn3[lane + 64], h3b = bn3[192 + lane];
  const float ba = b3[lane], bb = b3[lane + 64];
  float m0 = -1e30f, m1 = -1e30f;
  for (int k = 0; k < K_; k++) {
    size_t r = (size_t)gq * K_ + k;
    float v = y2[r * 64 + lane];
    float z = fmaxf(fmaf(v, isc, ish), 0.f);
    float a0 = ba, a1 = bb, c0 = 0.f, c1 = 0.f;
#pragma unroll
    for (int c = 0; c < 64; c += 2) {
      float z0 = rlf(z, c), z1 = rlf(z, c + 1);
      a0 = fmaf(z0, w0[c], a0);     a1 = fmaf(z0, w1[c], a1);
      c0 = fmaf(z1, w0[c + 1], c0); c1 = fmaf(z1, w1[c + 1], c1);
    }
    a0 += c0; a1 += c1;
    m0 = fmaxf(m0, fmaxf(fmaf(a0, s3a, h3a), 0.f));
    m1 = fmaxf(m1, fmaxf(fmaf(a1, s3b, h3b), 0.f));
  }
  __shared__ float tile[128 * 4];   // [ch][s_local]
  tile[lane * 4 + wv] = m0;
  tile[(lane + 64) * 4 + wv] = m1;
  __syncthreads();
  if (threadIdx.x < 128) {
    int b = blockIdx.x >> 8;            // 256 blocks per batch
    int s0i = (blockIdx.x & 255) * 4;
    float4 vv = *(float4*)&tile[threadIdx.x * 4];
    *(float4*)&out1[((size_t)b * 128 + threadIdx.x) * 1024 + s0i] = vv;
  }
}

extern "C" void kernel_launch(void* const* d_in, const int* in_sizes, int n_in,
                              void* d_out, int out_size, void* d_ws, size_t ws_size,
                              hipStream_t stream) {
  const float* xyz = (const float*)d_in[0];
  const float* pts = (const float*)d_in[1];
  const float* W1 = (const float*)d_in[2],  *b1 = (const float*)d_in[3];
  const float* g1 = (const float*)d_in[4],  *be1 = (const float*)d_in[5];
  const float* W2 = (const float*)d_in[6],  *b2 = (const float*)d_in[7];
  const float* g2 = (const float*)d_in[8],  *be2 = (const float*)d_in[9];
  const float* W3 = (const float*)d_in[10], *b3 = (const float*)d_in[11];
  const float* g3 = (const float*)d_in[12], *be3 = (const float*)d_in[13];
  float* out0 = (float*)d_out;                 // xyz_query_pc [16,3,1024]
  float* out1 = out0 + B_ * 3 * S_;            // new_points   [16,128,1024]

  char* ws = (char*)d_ws;
  float* new_xyz  = (float*)(ws);              // 49152 floats
  float* bn1      = (float*)(ws + 196608);     // 128
  float* bn2      = bn1 + 128;                 // 128
  float* bn3      = bn2 + 128;                 // 256
  int*   gidx     = (int*)(ws + 198656);       // 524288 ints
  float* partials = (float*)(ws + 2295808);    // 256*PN floats max
  float* y        = (float*)(ws + 4392960);    // 524288*64 floats (y1, then y2 in-place)

  fps_kernel<<<B_, 512, 0, stream>>>(xyz, out0, new_xyz);
  ballq_kernel<<<4096, 256, 0, stream>>>(xyz, new_xyz, gidx);
  layer1_kernel<<<PN, 256, 0, stream>>>(xyz, pts, new_xyz, gidx, W1, b1, y, partials);
  finalize_kernel<<<64, 256, 0, stream>>>(partials, 64, g1, be1, bn1);
  layer64_kernel<1, true><<<PN, 256, 0, stream>>>(y, W2, b2, bn1, y, partials, ROWS);
  finalize_kernel<<<64, 256, 0, stream>>>(partials, 64, g2, be2, bn2);
  layer64_kernel<2, false><<<PN, 256, 0, stream>>>(y, W3, b3, bn2, nullptr, partials, ROWS);
  finalize_kernel<<<128, 256, 0, stream>>>(partials, 128, g3, be3, bn3);
  l3max_kernel<<<4096, 256, 0, stream>>>(y, W3, b3, bn2, bn3, out1);
}

// Round 5
// 985.098 us; speedup vs baseline: 3.7378x; 1.3803x over previous
//
#include <hip/hip_runtime.h>

#pragma clang fp contract(off)

#define NPT 4096
#define B_ 16
#define S_ 1024
#define K_ 32
#define ROWS (B_*S_*K_)   // 524288
#define PNB 1024          // partial-stats blocks (layer kernels' grid)

typedef float v2f __attribute__((ext_vector_type(2)));
typedef unsigned int u32;
typedef unsigned long long u64;
typedef __attribute__((ext_vector_type(8))) short s16x8;
typedef __attribute__((ext_vector_type(4))) float f32x4;
typedef __attribute__((ext_vector_type(8))) unsigned short us8v;

// float readlane broadcast (SALU v_readlane -> scalar operand in FMA)
__device__ __forceinline__ float rlf(float v, int l) {
  return __uint_as_float(__builtin_amdgcn_readlane(__float_as_uint(v), l));
}

__device__ __forceinline__ short rne_bf16(float x) {
  u32 b = __float_as_uint(x);
  b += 0x7FFFu + ((b >> 16) & 1u);
  return (short)(b >> 16);
}
__device__ __forceinline__ float bf16_to_f(unsigned short h) {
  return __uint_as_float(((u32)h) << 16);
}

__device__ __forceinline__ f32x4 mfma16(s16x8 a, s16x8 b, f32x4 c) {
  return __builtin_amdgcn_mfma_f32_16x16x32_bf16(a, b, c, 0, 0, 0);
}

template <int CTRL>
__device__ __forceinline__ u64 dpp_u64(u64 x) {
  int lo = (int)(u32)x, hi = (int)(u32)(x >> 32);
  lo = __builtin_amdgcn_update_dpp(lo, lo, CTRL, 0xF, 0xF, false);
  hi = __builtin_amdgcn_update_dpp(hi, hi, CTRL, 0xF, 0xF, false);
  return ((u64)(u32)hi << 32) | (u32)lo;
}
// full-wave f64 max -> lane 63. Keys are positive doubles => f64 order == u64 order.
__device__ __forceinline__ double wave_max_f64(double k) {
  k = fmax(k, __longlong_as_double((long long)dpp_u64<0x111>((u64)__double_as_longlong(k))));
  k = fmax(k, __longlong_as_double((long long)dpp_u64<0x112>((u64)__double_as_longlong(k))));
  k = fmax(k, __longlong_as_double((long long)dpp_u64<0x114>((u64)__double_as_longlong(k))));
  k = fmax(k, __longlong_as_double((long long)dpp_u64<0x118>((u64)__double_as_longlong(k))));
  k = fmax(k, __longlong_as_double((long long)dpp_u64<0x142>((u64)__double_as_longlong(k))));
  k = fmax(k, __longlong_as_double((long long)dpp_u64<0x143>((u64)__double_as_longlong(k))));
  return k;
}

__device__ __forceinline__ double mkkey(float d, u32 lo) {
  return __longlong_as_double((long long)(((u64)__float_as_uint(d) << 32) | lo));
}

// ---------------- FPS: one block per batch, 512 threads, 8 pts/thread ----------------
__global__ __launch_bounds__(512) void fps_kernel(const float* __restrict__ xyz,
    float* __restrict__ out0, float* __restrict__ new_xyz) {
  const int b = blockIdx.x, t = threadIdx.x;
  const int lane = t & 63;
  const float* xb = xyz + (size_t)b * 3 * NPT;
  __shared__ float4 spt[NPT];       // 64 KB: (x,y,z,-)
  __shared__ u64 skey[3];           // 3-slot rotating argmax cell
  __shared__ int sfar[S_];          // selected index per iteration
  // coalesced stage into LDS
#pragma unroll
  for (int j = 0; j < 8; j++) {
    int m = t + j * 512;
    spt[m] = make_float4(xb[m], xb[NPT + m], xb[2 * NPT + m], 0.f);
  }
  if (t < 3) skey[t] = 0ull;
  // lane-local consecutive points n = t*8+i, loaded from GLOBAL (avoids LDS 64-way conflict)
  const float4* xb4 = (const float4*)xb;
  float4 X0 = xb4[t * 2], X1 = xb4[t * 2 + 1];
  float4 Y0 = xb4[NPT / 4 + t * 2], Y1 = xb4[NPT / 4 + t * 2 + 1];
  float4 Z0 = xb4[2 * NPT / 4 + t * 2], Z1 = xb4[2 * NPT / 4 + t * 2 + 1];
  v2f px[4], py[4], pz[4], ds[4];
  px[0] = (v2f){X0.x, X0.y}; px[1] = (v2f){X0.z, X0.w}; px[2] = (v2f){X1.x, X1.y}; px[3] = (v2f){X1.z, X1.w};
  py[0] = (v2f){Y0.x, Y0.y}; py[1] = (v2f){Y0.z, Y0.w}; py[2] = (v2f){Y1.x, Y1.y}; py[3] = (v2f){Y1.z, Y1.w};
  pz[0] = (v2f){Z0.x, Z0.y}; pz[1] = (v2f){Z0.z, Z0.w}; pz[2] = (v2f){Z1.x, Z1.y}; pz[3] = (v2f){Z1.z, Z1.w};
  const int base = t * 8;
  u32 lo[8];
#pragma unroll
  for (int i = 0; i < 8; i++) lo[i] = ~(u32)(base + i);
#pragma unroll
  for (int j = 0; j < 4; j++) ds[j] = (v2f){1e10f, 1e10f};
  __syncthreads();
  int far = 0, slot = 0;
  for (int it = 0; it < S_; ++it) {
    if (t == 0) sfar[it] = far;
    float4 c = spt[far];
    v2f cx = (v2f){c.x, c.x}, cy = (v2f){c.y, c.y}, cz = (v2f){c.z, c.z};
#pragma unroll
    for (int j = 0; j < 4; j++) {
      // exact ref op order per element: ((dx*dx + dy*dy) + dz*dz), contraction OFF
      v2f dx = px[j] - cx, dy = py[j] - cy, dz = pz[j] - cz;
      v2f s = dx * dx + dy * dy;
      v2f d = s + dz * dz;
      v2f nd;
      nd.x = fminf(ds[j].x, d.x);
      nd.y = fminf(ds[j].y, d.y);
      ds[j] = nd;
    }
    // f64 sortable keys: max dist, tie -> min index (via ~idx in low word)
    double k = fmax(fmax(fmax(mkkey(ds[0].x, lo[0]), mkkey(ds[0].y, lo[1])),
                         fmax(mkkey(ds[1].x, lo[2]), mkkey(ds[1].y, lo[3]))),
                    fmax(fmax(mkkey(ds[2].x, lo[4]), mkkey(ds[2].y, lo[5])),
                         fmax(mkkey(ds[3].x, lo[6]), mkkey(ds[3].y, lo[7]))));
    k = wave_max_f64(k);
    if (lane == 63) atomicMax(&skey[slot], (u64)__double_as_longlong(k));
    __syncthreads();
    u64 kk = skey[slot];
    if (t == 0) skey[slot == 0 ? 2 : slot - 1] = 0ull;  // reset slot (it+2)%3: safe post-barrier
    far = (int)(~(u32)kk);
    slot = (slot == 2) ? 0 : slot + 1;
  }
  __syncthreads();
  // coalesced writeback of centroids
#pragma unroll
  for (int j = 0; j < 2; j++) {
    int it = t + j * 512;
    float4 p = spt[sfar[it]];
    out0[(b * 3 + 0) * S_ + it] = p.x;
    out0[(b * 3 + 1) * S_ + it] = p.y;
    out0[(b * 3 + 2) * S_ + it] = p.z;
    float* nz = new_xyz + ((size_t)b * S_ + it) * 3;
    nz[0] = p.x; nz[1] = p.y; nz[2] = p.z;
  }
}

// ---------------- Ball query: one wave per query ----------------
__global__ __launch_bounds__(256) void ballq_kernel(const float* __restrict__ xyz,
    const float* __restrict__ new_xyz, int* __restrict__ gidx) {
  const int wid = (blockIdx.x * 256 + threadIdx.x) >> 6;   // 16384 queries
  const int lane = threadIdx.x & 63;
  const int b = wid >> 10;
  const float* xb = xyz + (size_t)b * 3 * NPT;
  const float qx = new_xyz[(size_t)wid * 3 + 0];
  const float qy = new_xyz[(size_t)wid * 3 + 1];
  const float qz = new_xyz[(size_t)wid * 3 + 2];
  const float R2 = (float)(0.4 * 0.4);
  int* g = gidx + (size_t)wid * K_;
  int cnt = 0, firstIdx = 0x7fffffff;
  for (int c0 = 0; c0 < NPT && cnt < K_; c0 += 64) {
    int n = c0 + lane;
    float dx = __fadd_rn(qx, -xb[n]);
    float dy = __fadd_rn(qy, -xb[NPT + n]);
    float dz = __fadd_rn(qz, -xb[2 * NPT + n]);
    float sq = __fadd_rn(__fadd_rn(__fmul_rn(dx, dx), __fmul_rn(dy, dy)), __fmul_rn(dz, dz));
    bool inr = !(sq > R2);
    unsigned long long m = __ballot(inr);
    if (inr) {
      int pos = cnt + (int)__popcll(m & ((1ull << lane) - 1ull));
      if (pos < K_) g[pos] = n;
    }
    if (firstIdx == 0x7fffffff && m) firstIdx = c0 + (int)__builtin_ctzll(m);
    cnt += (int)__popcll(m);
  }
  if (lane >= cnt && lane < K_) g[lane] = firstIdx;  // pad with first (always exists: self)
}

// ---------------- Layer 1: gather+concat fused, 6->64, bf16 out + partial stats ----------------
__global__ __launch_bounds__(256) void layer1_kernel(
    const float* __restrict__ xyz, const float* __restrict__ pts,
    const float* __restrict__ new_xyz, const int* __restrict__ gidx,
    const float* __restrict__ W1, const float* __restrict__ b1,
    unsigned short* __restrict__ y1, float* __restrict__ partials) {
  __shared__ float sp[4 * 2 * 64];
  const int lane = threadIdx.x & 63, wv = threadIdx.x >> 6;
  const int nw = gridDim.x * 4;
  float w[6];
#pragma unroll
  for (int c = 0; c < 6; c++) w[c] = W1[lane * 6 + c];
  const float bias = b1[lane];
  float s0 = 0.f, s1 = 0.f;
  for (int r = blockIdx.x * 4 + wv; r < ROWS; r += nw) {
    int gi = gidx[r];
    int bs = r >> 5, b = bs >> 10;
    float v = 0.f;
    if (lane < 3)      v = xyz[((size_t)b * 3 + lane) * NPT + gi] - new_xyz[(size_t)bs * 3 + lane];
    else if (lane < 6) v = pts[((size_t)b * 3 + (lane - 3)) * NPT + gi];
    float acc = bias;
#pragma unroll
    for (int c = 0; c < 6; c++) acc = fmaf(rlf(v, c), w[c], acc);
    y1[(size_t)r * 64 + lane] = (unsigned short)rne_bf16(acc);
    s0 += acc; s1 = fmaf(acc, acc, s1);
  }
  sp[(wv * 2 + 0) * 64 + lane] = s0;
  sp[(wv * 2 + 1) * 64 + lane] = s1;
  __syncthreads();
  if (threadIdx.x < 128) {
    float p = sp[threadIdx.x] + sp[threadIdx.x + 128] + sp[threadIdx.x + 256] + sp[threadIdx.x + 384];
    partials[(size_t)threadIdx.x * PNB + blockIdx.x] = p;   // transposed: [stat_row][block]
  }
}

// ---------------- MFMA layer: bn(prev)+relu -> bf16 -> GEMM(64->NT*16) + stats ----------------
template <int NT, bool WRITE_OUT>
__global__ __launch_bounds__(256) void mfma_layer_kernel(
    const unsigned short* __restrict__ yin,   // [M][64] bf16 pre-BN
    const float* __restrict__ W,              // [NT*16][64] f32
    const float* __restrict__ bias,           // [NT*16]
    const float* __restrict__ bnin,           // scale[64], shift[64]
    unsigned short* __restrict__ yout,        // [M][NT*16] bf16 pre-BN (or unused)
    float* __restrict__ partials) {
  constexpr int COUT = NT * 16;
  const int lane = threadIdx.x & 63, wv = threadIdx.x >> 6;
  const int quad = lane >> 4, l16 = lane & 15;
  // loop-invariants: B-frags (W is [n][k] = exactly B-operand layout), bias, input BN
  s16x8 bfrag[NT][2];
  float biasr[NT];
#pragma unroll
  for (int t = 0; t < NT; t++) {
    int n = l16 + 16 * t;
    biasr[t] = bias[n];
#pragma unroll
    for (int kc = 0; kc < 2; kc++)
#pragma unroll
      for (int j = 0; j < 8; j++)
        bfrag[t][kc][j] = rne_bf16(W[(size_t)n * 64 + kc * 32 + quad * 8 + j]);
  }
  float isc[2][8], ish[2][8];
#pragma unroll
  for (int kc = 0; kc < 2; kc++)
#pragma unroll
    for (int j = 0; j < 8; j++) {
      int k = kc * 32 + quad * 8 + j;
      isc[kc][j] = bnin[k]; ish[kc][j] = bnin[64 + k];
    }
  float s0[NT], s1[NT];
#pragma unroll
  for (int t = 0; t < NT; t++) { s0[t] = 0.f; s1[t] = 0.f; }
  const int nwaves = gridDim.x * 4;
  for (int mt = blockIdx.x * 4 + wv; mt < ROWS / 16; mt += nwaves) {
    int row = mt * 16 + l16;
    const unsigned short* p = yin + (size_t)row * 64 + quad * 8;
    us8v r0 = *(const us8v*)p;
    us8v r1 = *(const us8v*)(p + 32);
    s16x8 a0, a1;
#pragma unroll
    for (int j = 0; j < 8; j++) {
      float z0 = fmaxf(fmaf(bf16_to_f(r0[j]), isc[0][j], ish[0][j]), 0.f);
      float z1 = fmaxf(fmaf(bf16_to_f(r1[j]), isc[1][j], ish[1][j]), 0.f);
      a0[j] = rne_bf16(z0); a1[j] = rne_bf16(z1);
    }
    f32x4 acc[NT];
#pragma unroll
    for (int t = 0; t < NT; t++) {
      acc[t] = (f32x4){biasr[t], biasr[t], biasr[t], biasr[t]};
      acc[t] = mfma16(a0, bfrag[t][0], acc[t]);
      acc[t] = mfma16(a1, bfrag[t][1], acc[t]);
    }
#pragma unroll
    for (int t = 0; t < NT; t++) {
#pragma unroll
      for (int r = 0; r < 4; r++) {
        float v = acc[t][r];                       // D[row=quad*4+r][col=l16+16t]
        s0[t] += v; s1[t] = fmaf(v, v, s1[t]);
        if (WRITE_OUT) {
          int m = mt * 16 + quad * 4 + r;
          yout[(size_t)m * COUT + l16 + 16 * t] = (unsigned short)rne_bf16(v);
        }
      }
    }
  }
  // reduce stats: lanes {n, n+16, n+32, n+48} hold the same channel
#pragma unroll
  for (int t = 0; t < NT; t++) {
    s0[t] += __shfl_xor(s0[t], 16); s0[t] += __shfl_xor(s0[t], 32);
    s1[t] += __shfl_xor(s1[t], 16); s1[t] += __shfl_xor(s1[t], 32);
  }
  __shared__ float sp[4 * 2 * COUT];
  if (quad == 0) {
#pragma unroll
    for (int t = 0; t < NT; t++) {
      sp[wv * 2 * COUT + l16 + 16 * t] = s0[t];
      sp[wv * 2 * COUT + COUT + l16 + 16 * t] = s1[t];
    }
  }
  __syncthreads();
  for (int tt = threadIdx.x; tt < 2 * COUT; tt += 256) {
    float p = sp[tt] + sp[2 * COUT + tt] + sp[4 * COUT + tt] + sp[6 * COUT + tt];
    partials[(size_t)tt * PNB + blockIdx.x] = p;
  }
}

// ---------------- fold partials -> bn scale/shift (one block per channel) ----------------
__global__ __launch_bounds__(256) void finalize_kernel(const float* __restrict__ partials,
    int cout, const float* __restrict__ g, const float* __restrict__ be,
    float* __restrict__ bn) {
  const int c = blockIdx.x;
  const int t = threadIdx.x;
  const int lane = t & 63, wv = t >> 6;
  float s0 = 0.f, s1 = 0.f;
  for (int bb = t; bb < PNB; bb += 256) {
    s0 += partials[(size_t)c * PNB + bb];
    s1 += partials[(size_t)(cout + c) * PNB + bb];
  }
#pragma unroll
  for (int off = 32; off; off >>= 1) {
    s0 += __shfl_xor(s0, off);
    s1 += __shfl_xor(s1, off);
  }
  __shared__ float r0[4], r1[4];
  if (lane == 0) { r0[wv] = s0; r1[wv] = s1; }
  __syncthreads();
  if (t == 0) {
    double d0 = (double)r0[0] + r0[1] + r0[2] + r0[3];
    double d1 = (double)r1[0] + r1[1] + r1[2] + r1[3];
    double N = (double)ROWS;
    double mean = d0 / N;
    double var = d1 / N - mean * mean;
    double scale = (double)g[c] / sqrt(var + 1e-5);
    bn[c] = (float)scale;
    bn[cout + c] = (float)((double)be[c] - mean * scale);
  }
}

// ---------------- Layer3 recompute (MFMA) + bn3 + relu + max over K + transposed store ----------------
__global__ __launch_bounds__(256) void l3max_kernel(
    const unsigned short* __restrict__ y2, const float* __restrict__ W3,
    const float* __restrict__ b3, const float* __restrict__ bn2,
    const float* __restrict__ bn3, float* __restrict__ out1) {
  constexpr int NT = 8;
  const int lane = threadIdx.x & 63, wv = threadIdx.x >> 6;
  const int quad = lane >> 4, l16 = lane & 15;
  const int gq = blockIdx.x * 4 + wv;            // 16384 (b,s) groups
  s16x8 bfrag[NT][2];
  float biasr[NT], s3[NT], h3[NT];
#pragma unroll
  for (int t = 0; t < NT; t++) {
    int n = l16 + 16 * t;
    biasr[t] = b3[n]; s3[t] = bn3[n]; h3[t] = bn3[128 + n];
#pragma unroll
    for (int kc = 0; kc < 2; kc++)
#pragma unroll
      for (int j = 0; j < 8; j++)
        bfrag[t][kc][j] = rne_bf16(W3[(size_t)n * 64 + kc * 32 + quad * 8 + j]);
  }
  float isc[2][8], ish[2][8];
#pragma unroll
  for (int kc = 0; kc < 2; kc++)
#pragma unroll
    for (int j = 0; j < 8; j++) {
      int k = kc * 32 + quad * 8 + j;
      isc[kc][j] = bn2[k]; ish[kc][j] = bn2[64 + k];
    }
  float mx[NT];
#pragma unroll
  for (int t = 0; t < NT; t++) mx[t] = -1e30f;
#pragma unroll
  for (int mt2 = 0; mt2 < 2; mt2++) {            // 32 rows = 2 M-tiles
    int row = gq * 32 + mt2 * 16 + l16;
    const unsigned short* p = y2 + (size_t)row * 64 + quad * 8;
    us8v r0 = *(const us8v*)p;
    us8v r1 = *(const us8v*)(p + 32);
    s16x8 a0, a1;
#pragma unroll
    for (int j = 0; j < 8; j++) {
      float z0 = fmaxf(fmaf(bf16_to_f(r0[j]), isc[0][j], ish[0][j]), 0.f);
      float z1 = fmaxf(fmaf(bf16_to_f(r1[j]), isc[1][j], ish[1][j]), 0.f);
      a0[j] = rne_bf16(z0); a1[j] = rne_bf16(z1);
    }
#pragma unroll
    for (int t = 0; t < NT; t++) {
      f32x4 acc = (f32x4){biasr[t], biasr[t], biasr[t], biasr[t]};
      acc = mfma16(a0, bfrag[t][0], acc);
      acc = mfma16(a1, bfrag[t][1], acc);
#pragma unroll
      for (int r = 0; r < 4; r++) {
        float z = fmaxf(fmaf(acc[r], s3[t], h3[t]), 0.f);
        mx[t] = fmaxf(mx[t], z);
      }
    }
  }
#pragma unroll
  for (int t = 0; t < NT; t++) {
    mx[t] = fmaxf(mx[t], __shfl_xor(mx[t], 16));
    mx[t] = fmaxf(mx[t], __shfl_xor(mx[t], 32));
  }
  __shared__ float tile[128 * 4];   // [ch][s_local]
  if (quad == 0) {
#pragma unroll
    for (int t = 0; t < NT; t++) tile[(l16 + 16 * t) * 4 + wv] = mx[t];
  }
  __syncthreads();
  if (threadIdx.x < 128) {
    int b = blockIdx.x >> 8;            // 256 blocks per batch
    int s0i = (blockIdx.x & 255) * 4;
    float4 vv = *(float4*)&tile[threadIdx.x * 4];
    *(float4*)&out1[((size_t)b * 128 + threadIdx.x) * 1024 + s0i] = vv;
  }
}

extern "C" void kernel_launch(void* const* d_in, const int* in_sizes, int n_in,
                              void* d_out, int out_size, void* d_ws, size_t ws_size,
                              hipStream_t stream) {
  const float* xyz = (const float*)d_in[0];
  const float* pts = (const float*)d_in[1];
  const float* W1 = (const float*)d_in[2],  *b1 = (const float*)d_in[3];
  const float* g1 = (const float*)d_in[4],  *be1 = (const float*)d_in[5];
  const float* W2 = (const float*)d_in[6],  *b2 = (const float*)d_in[7];
  const float* g2 = (const float*)d_in[8],  *be2 = (const float*)d_in[9];
  const float* W3 = (const float*)d_in[10], *b3 = (const float*)d_in[11];
  const float* g3 = (const float*)d_in[12], *be3 = (const float*)d_in[13];
  float* out0 = (float*)d_out;                 // xyz_query_pc [16,3,1024]
  float* out1 = out0 + B_ * 3 * S_;            // new_points   [16,128,1024]

  char* ws = (char*)d_ws;
  float* new_xyz  = (float*)(ws);              // 49152 floats
  float* bn1      = (float*)(ws + 196608);     // 128
  float* bn2      = bn1 + 128;                 // 128
  float* bn3      = bn2 + 128;                 // 256
  int*   gidx     = (int*)(ws + 198656);       // 524288 ints
  float* partials = (float*)(ws + 2295808);    // 256*PNB floats (1 MB)
  unsigned short* y1 = (unsigned short*)(ws + 4392960);           // 64 MB bf16
  unsigned short* y2 = (unsigned short*)(ws + 4392960 + 67108864); // 64 MB bf16

  fps_kernel<<<B_, 512, 0, stream>>>(xyz, out0, new_xyz);
  ballq_kernel<<<4096, 256, 0, stream>>>(xyz, new_xyz, gidx);
  layer1_kernel<<<PNB, 256, 0, stream>>>(xyz, pts, new_xyz, gidx, W1, b1, y1, partials);
  finalize_kernel<<<64, 256, 0, stream>>>(partials, 64, g1, be1, bn1);
  mfma_layer_kernel<4, true><<<PNB, 256, 0, stream>>>(y1, W2, b2, bn1, y2, partials);
  finalize_kernel<<<64, 256, 0, stream>>>(partials, 64, g2, be2, bn2);
  mfma_layer_kernel<8, false><<<PNB, 256, 0, stream>>>(y2, W3, b3, bn2, nullptr, partials);
  finalize_kernel<<<128, 256, 0, stream>>>(partials, 128, g3, be3, bn3);
  l3max_kernel<<<4096, 256, 0, stream>>>(y2, W3, b3, bn2, bn3, out1);
}